// Round 9
// baseline (1118.519 us; speedup 1.0000x reference)
//
#include <hip/hip_runtime.h>

#define B_TOT   512
#define T_LEN   512
#define F_IN_D  8
#define H_DIM   128
#define OUT_DIM 7
#define TC      8                 // timesteps per chunk (xg register granularity)
#define NCHUNK  (T_LEN / TC)      // 64
#define RSLOT   16                // ring slots per layer boundary
#define BBATCH  16                // batch rows per block (full MFMA N)
#define NGRP    (B_TOT / BBATCH)  // 32 groups
#define NTHREADS 512              // 8 waves
#define SPIN_LIMIT (1 << 18)      // bounded waits: fail-visible, never hang

typedef __bf16 bf16x8 __attribute__((ext_vector_type(8)));
typedef __bf16 bf16x4 __attribute__((ext_vector_type(4)));
typedef float  f32x4  __attribute__((ext_vector_type(4)));
typedef unsigned long long u64;

// ---- workspace layout (bf16 element offsets) ----
#define WS_WHH   0                     // [3][32][4][64][8] = 196608
#define WS_WIH12 196608                // [2][32][4][64][8] = 131072
#define WS_WIH0  327680                // [32][64][8] = 16384 (k>=8 zero-padded)
#define WS_BIAS  344064                // float[3][512] combined b_ih+b_hh
#define WS_FLAGS 347136                // int[2][32] flags, then int[2][32] consumed
#define WS_BUF   347648                // [2][32] pair ring buffers
#define CH_ELEMS   (TC * BBATCH * H_DIM)   // 16384 bf16 per chunk (32 KB)
#define CH_U64     (CH_ELEMS / 4)          // 4096 u64 per chunk
#define PAIR_ELEMS (RSLOT * CH_ELEMS)      // 262144 (512 KiB per pair)

// h layout [kgroup][batch][8]: element (batch b, hdim k) at [k>>3][b][k&7].
// Step B-frag read (lane q,n16 needs k in [kc*32+q*8,+8), col n16) is a
// CONTIGUOUS 1KB wave read -> zero bank conflicts. Ring slots + the LDS ring
// mirror use the same layout: flush is a verbatim 32KB copy, staged reads are
// contiguous.
struct __align__(16) SharedMem {
  __bf16 h[2][16][16][8];     // [step parity][kgroup][batch][k&7]  (8 KB)
  __bf16 hist[TC][16][16][8]; // chunk h history, ring-slot layout  (32 KB)
  u64    ring[CH_U64];        // LDS mirror of upstream ring slot   (32 KB)
  float  z[16][H_DIM];        // fc1 output (layer-2 blocks only)   (8 KB)
};

__device__ __forceinline__ float sigf(float x) {
  return __builtin_amdgcn_rcpf(1.f + __expf(-x));
}
// sig(a) * tanh(x) with ONE rcp: (E-1) / ((1+e^-a)(E+1)), E = e^{2*clamp(x)}.
// Cuts gate trans issue from 10 to 8 ops/element (v_exp/v_rcp are quarter-rate).
__device__ __forceinline__ float sigmul(float a, float x) {
  const float xc = fminf(fmaxf(x, -15.f), 15.f);
  const float E  = __expf(2.f * xc);
  const float F  = __expf(-a);
  return (E - 1.f) * __builtin_amdgcn_rcpf((1.f + F) * (E + 1.f));
}
__device__ __forceinline__ bf16x8 load8_f32_bf16(const float* p) {
  const f32x4 a = *(const f32x4*)p;
  const f32x4 b = *(const f32x4*)(p + 4);
  bf16x8 r;
  #pragma unroll
  for (int j = 0; j < 4; ++j) { r[j] = (__bf16)a[j]; r[4 + j] = (__bf16)b[j]; }
  return r;
}
__device__ __forceinline__ bf16x8 zero_bf16x8() {
  bf16x8 r;
  #pragma unroll
  for (int j = 0; j < 8; ++j) r[j] = (__bf16)0.f;
  return r;
}
// All cross-block traffic is agent-scope RELAXED atomics -> coherent at the
// IC by construction (no wbl2/inv cache maintenance; R6 measured win).
// Ordering: the phase-C __syncthreads drains each thread's vmcnt(0)
// (compiler-guaranteed before s_barrier), so data atomics are complete at the
// coherence point before any flag atomic issued after it.
__device__ __forceinline__ int afl_load(int* p) {
  return __hip_atomic_load(p, __ATOMIC_RELAXED, __HIP_MEMORY_SCOPE_AGENT);
}
__device__ __forceinline__ void afl_store(int* p, int v) {
  __hip_atomic_store(p, v, __ATOMIC_RELAXED, __HIP_MEMORY_SCOPE_AGENT);
}
__device__ __forceinline__ u64 adat_load(const u64* p) {
  return __hip_atomic_load(p, __ATOMIC_RELAXED, __HIP_MEMORY_SCOPE_AGENT);
}
__device__ __forceinline__ void adat_store(u64* p, u64 v) {
  __hip_atomic_store(p, v, __ATOMIC_RELAXED, __HIP_MEMORY_SCOPE_AGENT);
}
// Bounded poll (single designated thread; phase-A barrier redistributes).
__device__ __forceinline__ void wait_ge(int* p, int v) {
  for (int it = 0; it < SPIN_LIMIT && afl_load(p) < v; ++it)
    __builtin_amdgcn_s_sleep(1);
}

// ---- prep: pack weights into frag order (bf16), combine biases, zero flags ----
__global__ void prep_kernel(const float* __restrict__ wih0, const float* __restrict__ whh0,
                            const float* __restrict__ bih0, const float* __restrict__ bhh0,
                            const float* __restrict__ wih1, const float* __restrict__ whh1,
                            const float* __restrict__ bih1, const float* __restrict__ bhh1,
                            const float* __restrict__ wih2, const float* __restrict__ whh2,
                            const float* __restrict__ bih2, const float* __restrict__ bhh2,
                            __bf16* __restrict__ ws)
{
  const float* WHH[3] = {whh0, whh1, whh2};
  const float* WIH[3] = {wih0, wih1, wih2};
  const float* BIH[3] = {bih0, bih1, bih2};
  const float* BHH[3] = {bhh0, bhh1, bhh2};
  const int NWHH = 3 * 32 * 4 * 64;   // 24576
  const int NWIH = 2 * 32 * 4 * 64;   // 16384
  const int NW0  = 32 * 64;           // 2048
  const int NBIA = 3 * 512;           // 1536
  const int NFLG = 128;               // flags + consumed
  const int TOTAL = NWHH + NWIH + NW0 + NBIA + NFLG;
  for (int idx = blockIdx.x * blockDim.x + threadIdx.x; idx < TOTAL;
       idx += gridDim.x * blockDim.x) {
    if (idx < NWHH) {
      const int lyr = idx >> 13, rem = idx & 8191;
      const int mt = rem >> 8, kc = (rem >> 6) & 3, lane = rem & 63;
      const int row = 16 * mt + (lane & 15);
      const int k0  = kc * 32 + (lane >> 4) * 8;
      const float* src = WHH[lyr] + row * H_DIM + k0;
      __bf16* dst = ws + WS_WHH + (size_t)idx * 8;
      #pragma unroll
      for (int j = 0; j < 8; ++j) dst[j] = (__bf16)src[j];
    } else if (idx < NWHH + NWIH) {
      const int i2 = idx - NWHH;
      const int lyr = (i2 >> 13) + 1, rem = i2 & 8191;
      const int mt = rem >> 8, kc = (rem >> 6) & 3, lane = rem & 63;
      const int row = 16 * mt + (lane & 15);
      const int k0  = kc * 32 + (lane >> 4) * 8;
      const float* src = WIH[lyr] + row * H_DIM + k0;
      __bf16* dst = ws + WS_WIH12 + (size_t)i2 * 8;
      #pragma unroll
      for (int j = 0; j < 8; ++j) dst[j] = (__bf16)src[j];
    } else if (idx < NWHH + NWIH + NW0) {
      const int i3 = idx - NWHH - NWIH;
      const int mt = i3 >> 6, lane = i3 & 63;
      const int row = 16 * mt + (lane & 15);
      const int k0  = (lane >> 4) * 8;
      __bf16* dst = ws + WS_WIH0 + (size_t)i3 * 8;
      #pragma unroll
      for (int j = 0; j < 8; ++j) {
        const int k = k0 + j;
        dst[j] = (k < F_IN_D) ? (__bf16)WIH[0][row * F_IN_D + k] : (__bf16)0.f;
      }
    } else if (idx < NWHH + NWIH + NW0 + NBIA) {
      const int i4 = idx - NWHH - NWIH - NW0;
      float* fb = (float*)(ws + WS_BIAS);
      fb[i4] = BIH[i4 >> 9][i4 & 511] + BHH[i4 >> 9][i4 & 511];
    } else {
      const int i5 = idx - NWHH - NWIH - NW0 - NBIA;
      ((int*)(ws + WS_FLAGS))[i5] = 0;
    }
  }
}

// R8c: the three R8 perf levers {TC 4->8 (per-chunk fixed cost amortized 2x),
// sigmul gate algebra (8 trans/elem vs 10), launch_bounds(512,1) for the
// xg[8][4] register budget} grafted onto the EXACT synchronization skeleton
// that passed in R5/R6/R7: phase-A = tid0-poll flag + tid64-poll backpressure
// + ONE barrier (R8's barrier-free desynced polls were the only structural
// novelty in the twice-container-failed R8/R8b; restored here to make the
// skeleton byte-identical to the passing lineage). Handshake semantics
// unchanged: flags=v => chunks [0,v) flushed & coherent; cons=v => consumer
// done reading chunks [0,v). All spins bounded: a protocol stall produces a
// wrong answer in ~1s, never an unbounded hang.
__global__ __launch_bounds__(NTHREADS, 1)
void lstm_kernel(const float* __restrict__ x,
                 const float* __restrict__ fc1w, const float* __restrict__ fc1b,
                 const float* __restrict__ fc2w, const float* __restrict__ fc2b,
                 float* __restrict__ out, __bf16* __restrict__ ws)
{
  __shared__ SharedMem sh;
  const int tid = threadIdx.x;
  const int w   = tid >> 6;   // wave 0..7
  const int l   = tid & 63;   // lane
  const int q   = l >> 4;     // quad 0..3
  const int n16 = l & 15;     // MFMA col = batch row within group
  const int lyr = blockIdx.x >> 5;   // 0..2
  const int g   = blockIdx.x & 31;   // batch group
  const int bg  = g * BBATCH;
  const int kg_w = 2 * w + (q >> 1); // kgroup this thread's h-rows land in
  const int sub  = (q & 1) * 4;      // sub-offset within the 8-elem kgroup

  int* flags = (int*)(ws + WS_FLAGS);
  int* cons  = flags + 64;
  const int myidx = (lyr < 2) ? lyr * NGRP + g : 0;
  const int upidx = (lyr > 0) ? (lyr - 1) * NGRP + g : 0;
  int* flag_my = &flags[myidx];
  int* flag_up = &flags[upidx];
  int* cons_my = &cons[myidx];
  int* cons_up = &cons[upidx];
  u64*       mybuf = (u64*)(ws + WS_BUF + (size_t)myidx * PAIR_ELEMS);
  const u64* upbuf = (const u64*)(ws + WS_BUF + (size_t)upidx * PAIR_ELEMS);

  // ---- resident whh fragments (the only persistent big register block) ----
  bf16x8 whhf[4][4];
  #pragma unroll
  for (int i = 0; i < 4; ++i)
    #pragma unroll
    for (int kc = 0; kc < 4; ++kc)
      whhf[i][kc] = *(const bf16x8*)(
          ws + WS_WHH + ((((size_t)lyr * 32 + (w + 8 * i)) * 4 + kc) * 64 + l) * 8);
  const float* fb = (const float*)(ws + WS_BIAS) + lyr * 512;

  // ---- zero initial h (parity 0 read at t=0) ----
  for (int e = tid; e < 2 * 16 * 16 * 8; e += NTHREADS)
    (&sh.h[0][0][0][0])[e] = (__bf16)0.f;
  f32x4 cst = {0.f, 0.f, 0.f, 0.f};   // cell state: rows 16w+4q+0..3, col n16
  __syncthreads();

  for (int c = 0; c < NCHUNK; ++c) {
    // ---- A) parallel waits + ONE barrier (R5/R6/R7-passing structure) ----
    if (lyr > 0 && tid == 0) wait_ge(flag_up, c + 1);           // upstream chunk c coherent
    if (lyr < 2 && c > RSLOT && tid == 64) wait_ge(cons_my, c - RSLOT); // slot for c-1 free
    __syncthreads();

    // ---- B) stage upstream slot c -> LDS ring (once), flush hist(c-1) ----
    if (lyr > 0) {
      const u64* src = upbuf + (size_t)(c % RSLOT) * CH_U64;
      #pragma unroll
      for (int it = 0; it < 8; ++it) {
        const int j = tid + it * NTHREADS;     // coalesced 8B x 64 lanes
        sh.ring[j] = adat_load(src + j);
      }
    }
    if (lyr < 2 && c > 0) {
      u64* dst = mybuf + (size_t)((c - 1) % RSLOT) * CH_U64;
      const u64* hsrc = (const u64*)&sh.hist[0][0][0][0];
      #pragma unroll
      for (int it = 0; it < 8; ++it) {
        const int j = tid + it * NTHREADS;     // 4096 u64 jobs, verbatim copy
        adat_store(dst + j, hsrc[j]);
      }
    }

    // ---- C) barrier drains vmcnt(0)+lgkmcnt(0) for ALL threads: stage
    //         ds_writes visible, flush stores complete at IC, slot-c reads
    //         done. Flag publishes after it are globally ordered. ----
    __syncthreads();
    if (lyr < 2 && c > 0 && tid == 0) afl_store(flag_my, c);
    if (lyr > 0 && tid == 0) afl_store(cons_up, c + 1);

    // ---- P) prologue: xg(c) into registers (C-init layout) ----
    f32x4 xg[TC][4];
    #pragma unroll
    for (int i = 0; i < 4; ++i) {
      const f32x4 bv = *(const f32x4*)(fb + 16 * (w + 8 * i) + 4 * q);
      #pragma unroll
      for (int s = 0; s < TC; ++s) xg[s][i] = bv;
    }

    if (lyr == 0) {
      bf16x8 wih0f[4];
      #pragma unroll
      for (int i = 0; i < 4; ++i)
        wih0f[i] = *(const bf16x8*)(ws + WS_WIH0 + ((size_t)(w + 8 * i) * 64 + l) * 8);
      #pragma unroll
      for (int s = 0; s < TC; ++s) {
        bf16x8 bfrag = zero_bf16x8();
        if (q == 0)      // k = q*8+j < 8 only in quad 0; weights zero-padded past 8
          bfrag = load8_f32_bf16(x + ((size_t)(bg + n16) * T_LEN + c * TC + s) * F_IN_D);
        #pragma unroll
        for (int i = 0; i < 4; ++i)
          xg[s][i] = __builtin_amdgcn_mfma_f32_16x16x32_bf16(wih0f[i], bfrag, xg[s][i], 0, 0, 0);
      }
    } else {
      const __bf16* rb = (const __bf16*)sh.ring;
      #pragma unroll
      for (int kc = 0; kc < 4; ++kc) {
        bf16x8 wf[4];
        #pragma unroll
        for (int i = 0; i < 4; ++i)
          wf[i] = *(const bf16x8*)(ws + WS_WIH12 +
              ((((size_t)(lyr - 1) * 32 + (w + 8 * i)) * 4 + kc) * 64 + l) * 8);
        #pragma unroll
        for (int s = 0; s < TC; ++s) {
          // contiguous 1KB wave read: lane (q,n16) -> ring[s][kc*4+q][n16][0..8)
          const bf16x8 bfrag =
              *(const bf16x8*)&rb[((s * 16 + kc * 4 + q) * 16 + n16) * 8];
          #pragma unroll
          for (int i = 0; i < 4; ++i)
            xg[s][i] = __builtin_amdgcn_mfma_f32_16x16x32_bf16(wf[i], bfrag, xg[s][i], 0, 0, 0);
        }
      }
    }

    // ---- D) TC recurrence steps: MFMA + in-register gates, ONE barrier ----
    #pragma unroll
    for (int s = 0; s < TC; ++s) {
      const int cur = s & 1, nxt = cur ^ 1;
      f32x4 acc[4];
      #pragma unroll
      for (int k = 0; k < 4; ++k) acc[k] = xg[s][k];
      #pragma unroll
      for (int kc = 0; kc < 4; ++kc) {
        // contiguous 1KB wave read: lane (q,n16) -> h[cur][kc*4+q][n16][0..8)
        const bf16x8 bfrag = *(const bf16x8*)&sh.h[cur][kc * 4 + q][n16][0];
        #pragma unroll
        for (int k = 0; k < 4; ++k)
          acc[k] = __builtin_amdgcn_mfma_f32_16x16x32_bf16(whhf[k][kc], bfrag, acc[k], 0, 0, 0);
      }
      // in-register gates: acc[0..3][r] = i,f,g,o for j=16w+4q+r, batch n16
      bf16x4 hb;
      #pragma unroll
      for (int r = 0; r < 4; ++r) {
        cst[r] = sigf(acc[1][r]) * cst[r] + sigmul(acc[0][r], acc[2][r]);
        hb[r]  = (__bf16)sigmul(acc[3][r], cst[r]);
      }
      *(bf16x4*)&sh.h[nxt][kg_w][n16][sub] = hb;
      if (lyr < 2) *(bf16x4*)&sh.hist[s][kg_w][n16][sub] = hb;
      __syncthreads();
    }
  }

  // ---- final flush of hist(NCHUNK-1) + terminal flag ----
  if (lyr < 2) {
    const int m = NCHUNK - 1;
    if (tid == 0) wait_ge(cons_my, m - RSLOT + 1);
    __syncthreads();
    u64* dst = mybuf + (size_t)(m % RSLOT) * CH_U64;
    const u64* hsrc = (const u64*)&sh.hist[0][0][0][0];
    #pragma unroll
    for (int it = 0; it < 8; ++it) {
      const int j = tid + it * NTHREADS;
      adat_store(dst + j, hsrc[j]);
    }
    __syncthreads();   // drains vmcnt(0): data at IC before flag
    if (tid == 0) afl_store(flag_my, NCHUNK);
  }

  // ---- FC head: layer-2 blocks; t=511 (s=7) wrote parity 0 ----
  if (lyr == 2) {
    for (int j = tid; j < BBATCH * H_DIM; j += NTHREADS) {
      const int b = j >> 7, i = j & 127;
      float a = fc1b[i];
      #pragma unroll 8
      for (int k = 0; k < H_DIM; ++k)
        a += (float)sh.h[0][k >> 3][b][k & 7] * fc1w[i * H_DIM + k];
      sh.z[b][i] = fmaxf(a, 0.f);
    }
    __syncthreads();
    if (tid < BBATCH * OUT_DIM) {
      const int b = tid / OUT_DIM, o = tid % OUT_DIM;
      float a = fc2b[o];
      for (int k = 0; k < H_DIM; ++k)
        a += sh.z[b][k] * fc2w[o * H_DIM + k];
      out[(size_t)(bg + b) * OUT_DIM + o] = a;
    }
  }
}

extern "C" void kernel_launch(void* const* d_in, const int* in_sizes, int n_in,
                              void* d_out, int out_size, void* d_ws, size_t ws_size,
                              hipStream_t stream) {
  const float* x    = (const float*)d_in[0];
  const float* wih0 = (const float*)d_in[1];
  const float* whh0 = (const float*)d_in[2];
  const float* bih0 = (const float*)d_in[3];
  const float* bhh0 = (const float*)d_in[4];
  const float* wih1 = (const float*)d_in[5];
  const float* whh1 = (const float*)d_in[6];
  const float* bih1 = (const float*)d_in[7];
  const float* bhh1 = (const float*)d_in[8];
  const float* wih2 = (const float*)d_in[9];
  const float* whh2 = (const float*)d_in[10];
  const float* bih2 = (const float*)d_in[11];
  const float* bhh2 = (const float*)d_in[12];
  const float* fc1w = (const float*)d_in[13];
  const float* fc1b = (const float*)d_in[14];
  const float* fc2w = (const float*)d_in[15];
  const float* fc2b = (const float*)d_in[16];
  float* out  = (float*)d_out;
  __bf16* ws  = (__bf16*)d_ws;   // ~33.7 MB used (weights + flags + 32 MB ring)

  prep_kernel<<<dim3(175), dim3(256), 0, stream>>>(
      wih0, whh0, bih0, bhh0, wih1, whh1, bih1, bhh1,
      wih2, whh2, bih2, bhh2, ws);
  lstm_kernel<<<dim3(3 * NGRP), dim3(NTHREADS), 0, stream>>>(
      x, fc1w, fc1b, fc2w, fc2b, out, ws);
}

// Round 11
// 832.009 us; speedup vs baseline: 1.3444x; 1.3444x over previous
//
#include <hip/hip_runtime.h>

#define B_TOT   512
#define T_LEN   512
#define F_IN_D  8
#define H_DIM   128
#define OUT_DIM 7
#define TC      8                 // timesteps per chunk
#define NCHUNK  (T_LEN / TC)      // 64
#define RSLOT   16                // ring slots per layer boundary
#define BBATCH  16                // batch rows per block (full MFMA N)
#define NGRP    (B_TOT / BBATCH)  // 32 groups
#define NTHREADS 512              // 8 waves
#define SPIN_LIMIT (1 << 18)      // bounded waits: fail-visible, never hang

typedef __bf16 bf16x8 __attribute__((ext_vector_type(8)));
typedef __bf16 bf16x4 __attribute__((ext_vector_type(4)));
typedef float  f32x4  __attribute__((ext_vector_type(4)));
typedef unsigned long long u64;

// ---- workspace layout (bf16 element offsets) ----
#define WS_WHH   0                     // [3][32][4][64][8] = 196608
#define WS_WIH12 196608                // [2][32][4][64][8] = 131072
#define WS_WIH0  327680                // [32][64][8] = 16384 (k>=8 zero-padded)
#define WS_BIAS  344064                // float[3][512] combined b_ih+b_hh
#define WS_FLAGS 347136                // int[2][32] flags, then int[2][32] consumed
#define WS_BUF   347648                // [2][32] pair ring buffers
#define CH_ELEMS   (TC * BBATCH * H_DIM)   // 16384 bf16 per chunk (32 KB)
#define CH_U64     (CH_ELEMS / 4)          // 4096 u64 per chunk
#define PAIR_ELEMS (RSLOT * CH_ELEMS)      // 262144 (512 KiB per pair)

// h layout [kgroup][batch][8]: element (batch b, hdim k) at [k>>3][b][k&7].
// Step B-frag read (lane q,n16 needs k in [kc*32+q*8,+8), col n16) is a
// CONTIGUOUS 1KB wave read -> zero bank conflicts. Ring slots + the LDS ring
// mirror use the same layout: flush is a verbatim 32KB copy, staged reads are
// contiguous.
struct __align__(16) SharedMem {
  __bf16 h[2][16][16][8];     // [step parity][kgroup][batch][k&7]  (8 KB)
  __bf16 hist[TC][16][16][8]; // chunk h history, ring-slot layout  (32 KB)
  u64    ring[CH_U64];        // LDS mirror of upstream ring slot   (32 KB)
  float  z[16][H_DIM];        // fc1 output (layer-2 blocks only)   (8 KB)
};

__device__ __forceinline__ float sigf(float x) {
  return __builtin_amdgcn_rcpf(1.f + __expf(-x));
}
// sig(a) * tanh(x) with ONE rcp: (E-1) / ((1+e^-a)(E+1)), E = e^{2*clamp(x)}.
// Cuts gate trans issue from 10 to 8 ops/element (v_exp/v_rcp are quarter-rate).
__device__ __forceinline__ float sigmul(float a, float x) {
  const float xc = fminf(fmaxf(x, -15.f), 15.f);
  const float E  = __expf(2.f * xc);
  const float F  = __expf(-a);
  return (E - 1.f) * __builtin_amdgcn_rcpf((1.f + F) * (E + 1.f));
}
__device__ __forceinline__ bf16x8 load8_f32_bf16(const float* p) {
  const f32x4 a = *(const f32x4*)p;
  const f32x4 b = *(const f32x4*)(p + 4);
  bf16x8 r;
  #pragma unroll
  for (int j = 0; j < 4; ++j) { r[j] = (__bf16)a[j]; r[4 + j] = (__bf16)b[j]; }
  return r;
}
__device__ __forceinline__ bf16x8 zero_bf16x8() {
  bf16x8 r;
  #pragma unroll
  for (int j = 0; j < 8; ++j) r[j] = (__bf16)0.f;
  return r;
}
// All cross-block traffic is agent-scope RELAXED atomics -> coherent at the
// IC by construction (no wbl2/inv cache maintenance; R6 measured win).
// Ordering: the phase-C __syncthreads drains each thread's vmcnt(0)
// (compiler-guaranteed before s_barrier), so data atomics are complete at the
// coherence point before any flag atomic issued after it.
__device__ __forceinline__ int afl_load(int* p) {
  return __hip_atomic_load(p, __ATOMIC_RELAXED, __HIP_MEMORY_SCOPE_AGENT);
}
__device__ __forceinline__ void afl_store(int* p, int v) {
  __hip_atomic_store(p, v, __ATOMIC_RELAXED, __HIP_MEMORY_SCOPE_AGENT);
}
__device__ __forceinline__ u64 adat_load(const u64* p) {
  return __hip_atomic_load(p, __ATOMIC_RELAXED, __HIP_MEMORY_SCOPE_AGENT);
}
__device__ __forceinline__ void adat_store(u64* p, u64 v) {
  __hip_atomic_store(p, v, __ATOMIC_RELAXED, __HIP_MEMORY_SCOPE_AGENT);
}
// Bounded poll (single designated thread; phase-A barrier redistributes).
__device__ __forceinline__ void wait_ge(int* p, int v) {
  for (int it = 0; it < SPIN_LIMIT && afl_load(p) < v; ++it)
    __builtin_amdgcn_s_sleep(1);
}

// ---- prep: pack weights into frag order (bf16), combine biases, zero flags ----
__global__ void prep_kernel(const float* __restrict__ wih0, const float* __restrict__ whh0,
                            const float* __restrict__ bih0, const float* __restrict__ bhh0,
                            const float* __restrict__ wih1, const float* __restrict__ whh1,
                            const float* __restrict__ bih1, const float* __restrict__ bhh1,
                            const float* __restrict__ wih2, const float* __restrict__ whh2,
                            const float* __restrict__ bih2, const float* __restrict__ bhh2,
                            __bf16* __restrict__ ws)
{
  const float* WHH[3] = {whh0, whh1, whh2};
  const float* WIH[3] = {wih0, wih1, wih2};
  const float* BIH[3] = {bih0, bih1, bih2};
  const float* BHH[3] = {bhh0, bhh1, bhh2};
  const int NWHH = 3 * 32 * 4 * 64;   // 24576
  const int NWIH = 2 * 32 * 4 * 64;   // 16384
  const int NW0  = 32 * 64;           // 2048
  const int NBIA = 3 * 512;           // 1536
  const int NFLG = 128;               // flags + consumed
  const int TOTAL = NWHH + NWIH + NW0 + NBIA + NFLG;
  for (int idx = blockIdx.x * blockDim.x + threadIdx.x; idx < TOTAL;
       idx += gridDim.x * blockDim.x) {
    if (idx < NWHH) {
      const int lyr = idx >> 13, rem = idx & 8191;
      const int mt = rem >> 8, kc = (rem >> 6) & 3, lane = rem & 63;
      const int row = 16 * mt + (lane & 15);
      const int k0  = kc * 32 + (lane >> 4) * 8;
      const float* src = WHH[lyr] + row * H_DIM + k0;
      __bf16* dst = ws + WS_WHH + (size_t)idx * 8;
      #pragma unroll
      for (int j = 0; j < 8; ++j) dst[j] = (__bf16)src[j];
    } else if (idx < NWHH + NWIH) {
      const int i2 = idx - NWHH;
      const int lyr = (i2 >> 13) + 1, rem = i2 & 8191;
      const int mt = rem >> 8, kc = (rem >> 6) & 3, lane = rem & 63;
      const int row = 16 * mt + (lane & 15);
      const int k0  = kc * 32 + (lane >> 4) * 8;
      const float* src = WIH[lyr] + row * H_DIM + k0;
      __bf16* dst = ws + WS_WIH12 + (size_t)i2 * 8;
      #pragma unroll
      for (int j = 0; j < 8; ++j) dst[j] = (__bf16)src[j];
    } else if (idx < NWHH + NWIH + NW0) {
      const int i3 = idx - NWHH - NWIH;
      const int mt = i3 >> 6, lane = i3 & 63;
      const int row = 16 * mt + (lane & 15);
      const int k0  = (lane >> 4) * 8;
      __bf16* dst = ws + WS_WIH0 + (size_t)i3 * 8;
      #pragma unroll
      for (int j = 0; j < 8; ++j) {
        const int k = k0 + j;
        dst[j] = (k < F_IN_D) ? (__bf16)WIH[0][row * F_IN_D + k] : (__bf16)0.f;
      }
    } else if (idx < NWHH + NWIH + NW0 + NBIA) {
      const int i4 = idx - NWHH - NWIH - NW0;
      float* fb = (float*)(ws + WS_BIAS);
      fb[i4] = BIH[i4 >> 9][i4 & 511] + BHH[i4 >> 9][i4 & 511];
    } else {
      const int i5 = idx - NWHH - NWIH - NW0 - NBIA;
      ((int*)(ws + WS_FLAGS))[i5] = 0;
    }
  }
}

// R9b (R10 resubmit; round-10 failure was a dead ill-formed macro, removed).
// R8c precomputed xg[8][4] (128 f32 VGPRs live across the whole step loop) ->
// spilled to scratch (WRITE_SIZE +15MB, step chain reloads) and LOST 55us vs
// R7. Fix: software-pipeline xg INTO the step loop: xg(s) depends only on
// ring[c] (stable all chunk) + wih, NOT on the recurrence -- mini-prologue
// computes xg[0..1]; step s computes xg[s+2] (16 independent MFMAs on the
// otherwise-idle matrix pipe, off the serial chain). xg liveness <= 3 entries
// (48 VGPRs); the separate prologue phase disappears entirely. Sync skeleton
// (A/B/C phases, flags, cons, bounded spins) byte-identical to the 4x-passed
// R5/R6/R7/R8c lineage.
__global__ __launch_bounds__(NTHREADS, 1)
void lstm_kernel(const float* __restrict__ x,
                 const float* __restrict__ fc1w, const float* __restrict__ fc1b,
                 const float* __restrict__ fc2w, const float* __restrict__ fc2b,
                 float* __restrict__ out, __bf16* __restrict__ ws)
{
  __shared__ SharedMem sh;
  const int tid = threadIdx.x;
  const int w   = tid >> 6;   // wave 0..7
  const int l   = tid & 63;   // lane
  const int q   = l >> 4;     // quad 0..3
  const int n16 = l & 15;     // MFMA col = batch row within group
  const int lyr = blockIdx.x >> 5;   // 0..2
  const int g   = blockIdx.x & 31;   // batch group
  const int bg  = g * BBATCH;
  const int kg_w = 2 * w + (q >> 1); // kgroup this thread's h-rows land in
  const int sub  = (q & 1) * 4;      // sub-offset within the 8-elem kgroup

  int* flags = (int*)(ws + WS_FLAGS);
  int* cons  = flags + 64;
  const int myidx = (lyr < 2) ? lyr * NGRP + g : 0;
  const int upidx = (lyr > 0) ? (lyr - 1) * NGRP + g : 0;
  int* flag_my = &flags[myidx];
  int* flag_up = &flags[upidx];
  int* cons_my = &cons[myidx];
  int* cons_up = &cons[upidx];
  u64*       mybuf = (u64*)(ws + WS_BUF + (size_t)myidx * PAIR_ELEMS);
  const u64* upbuf = (const u64*)(ws + WS_BUF + (size_t)upidx * PAIR_ELEMS);

  // ---- resident weight fragments + bias (per-layer constants) ----
  bf16x8 whhf[4][4];   // recurrence weights: on the serial chain, stay resident
  #pragma unroll
  for (int i = 0; i < 4; ++i)
    #pragma unroll
    for (int kc = 0; kc < 4; ++kc)
      whhf[i][kc] = *(const bf16x8*)(
          ws + WS_WHH + ((((size_t)lyr * 32 + (w + 8 * i)) * 4 + kc) * 64 + l) * 8);
  f32x4 biasv[4];
  #pragma unroll
  for (int i = 0; i < 4; ++i)
    biasv[i] = *(const f32x4*)((const float*)(ws + WS_BIAS) + lyr * 512
                               + 16 * (w + 8 * i) + 4 * q);
  bf16x8 wf[4][4];     // input-proj weights (lyr>0 path); lyr0 uses wih0f
  bf16x8 wih0f[4];
  if (lyr == 0) {
    #pragma unroll
    for (int i = 0; i < 4; ++i)
      wih0f[i] = *(const bf16x8*)(ws + WS_WIH0 + ((size_t)(w + 8 * i) * 64 + l) * 8);
  } else {
    #pragma unroll
    for (int i = 0; i < 4; ++i)
      #pragma unroll
      for (int kc = 0; kc < 4; ++kc)
        wf[i][kc] = *(const bf16x8*)(ws + WS_WIH12 +
            ((((size_t)(lyr - 1) * 32 + (w + 8 * i)) * 4 + kc) * 64 + l) * 8);
  }

  // ---- zero initial h (parity 0 read at t=0) ----
  for (int e = tid; e < 2 * 16 * 16 * 8; e += NTHREADS)
    (&sh.h[0][0][0][0])[e] = (__bf16)0.f;
  f32x4 cst = {0.f, 0.f, 0.f, 0.f};   // cell state: rows 16w+4q+0..3, col n16
  __syncthreads();

  for (int c = 0; c < NCHUNK; ++c) {
    // ---- A) parallel waits + ONE barrier (R5..R8c-passing structure) ----
    if (lyr > 0 && tid == 0) wait_ge(flag_up, c + 1);           // upstream chunk c coherent
    if (lyr < 2 && c > RSLOT && tid == 64) wait_ge(cons_my, c - RSLOT); // slot for c-1 free
    __syncthreads();

    // ---- B) stage upstream slot c -> LDS ring (once), flush hist(c-1) ----
    if (lyr > 0) {
      const u64* src = upbuf + (size_t)(c % RSLOT) * CH_U64;
      #pragma unroll
      for (int it = 0; it < 8; ++it) {
        const int j = tid + it * NTHREADS;     // coalesced 8B x 64 lanes
        sh.ring[j] = adat_load(src + j);
      }
    }
    if (lyr < 2 && c > 0) {
      u64* dst = mybuf + (size_t)((c - 1) % RSLOT) * CH_U64;
      const u64* hsrc = (const u64*)&sh.hist[0][0][0][0];
      #pragma unroll
      for (int it = 0; it < 8; ++it) {
        const int j = tid + it * NTHREADS;     // 4096 u64 jobs, verbatim copy
        adat_store(dst + j, hsrc[j]);
      }
    }

    // ---- C) barrier drains vmcnt(0)+lgkmcnt(0) for ALL threads: stage
    //         ds_writes visible, flush stores complete at IC, slot-c reads
    //         done. Flag publishes after it are globally ordered. ----
    __syncthreads();
    if (lyr < 2 && c > 0 && tid == 0) afl_store(flag_my, c);
    if (lyr > 0 && tid == 0) afl_store(cons_up, c + 1);

    // ---- steps with software-pipelined xg (liveness <= 3 entries) ----
    const __bf16* rb = (const __bf16*)sh.ring;
    f32x4 xg[TC][4];

    // mini-prologue: xg[0], xg[1]
    #pragma unroll
    for (int t = 0; t < 2; ++t) {
      #pragma unroll
      for (int i = 0; i < 4; ++i) xg[t][i] = biasv[i];
      if (lyr == 0) {
        bf16x8 bfrag = zero_bf16x8();
        if (q == 0)
          bfrag = load8_f32_bf16(x + ((size_t)(bg + n16) * T_LEN + c * TC + t) * F_IN_D);
        #pragma unroll
        for (int i = 0; i < 4; ++i)
          xg[t][i] = __builtin_amdgcn_mfma_f32_16x16x32_bf16(wih0f[i], bfrag, xg[t][i], 0, 0, 0);
      } else {
        #pragma unroll
        for (int kc = 0; kc < 4; ++kc) {
          const bf16x8 bfrag =
              *(const bf16x8*)&rb[((t * 16 + kc * 4 + q) * 16 + n16) * 8];
          #pragma unroll
          for (int i = 0; i < 4; ++i)
            xg[t][i] = __builtin_amdgcn_mfma_f32_16x16x32_bf16(wf[i][kc], bfrag, xg[t][i], 0, 0, 0);
        }
      }
    }

    #pragma unroll
    for (int s = 0; s < TC; ++s) {
      const int cur = s & 1, nxt = cur ^ 1;
      // recurrence MFMAs (serial chain)
      f32x4 acc[4];
      #pragma unroll
      for (int k = 0; k < 4; ++k) acc[k] = xg[s][k];
      #pragma unroll
      for (int kc = 0; kc < 4; ++kc) {
        // contiguous 1KB wave read: lane (q,n16) -> h[cur][kc*4+q][n16][0..8)
        const bf16x8 bfrag = *(const bf16x8*)&sh.h[cur][kc * 4 + q][n16][0];
        #pragma unroll
        for (int k = 0; k < 4; ++k)
          acc[k] = __builtin_amdgcn_mfma_f32_16x16x32_bf16(whhf[k][kc], bfrag, acc[k], 0, 0, 0);
      }
      // pipelined xg(s+2): independent of acc; fills matrix-pipe slack
      if (s < TC - 2) {
        const int t = s + 2;
        #pragma unroll
        for (int i = 0; i < 4; ++i) xg[t][i] = biasv[i];
        if (lyr == 0) {
          bf16x8 bfrag = zero_bf16x8();
          if (q == 0)
            bfrag = load8_f32_bf16(x + ((size_t)(bg + n16) * T_LEN + c * TC + t) * F_IN_D);
          #pragma unroll
          for (int i = 0; i < 4; ++i)
            xg[t][i] = __builtin_amdgcn_mfma_f32_16x16x32_bf16(wih0f[i], bfrag, xg[t][i], 0, 0, 0);
        } else {
          #pragma unroll
          for (int kc = 0; kc < 4; ++kc) {
            const bf16x8 bfrag =
                *(const bf16x8*)&rb[((t * 16 + kc * 4 + q) * 16 + n16) * 8];
            #pragma unroll
            for (int i = 0; i < 4; ++i)
              xg[t][i] = __builtin_amdgcn_mfma_f32_16x16x32_bf16(wf[i][kc], bfrag, xg[t][i], 0, 0, 0);
          }
        }
      }
      // in-register gates: acc[0..3][r] = i,f,g,o for j=16w+4q+r, batch n16
      bf16x4 hb;
      #pragma unroll
      for (int r = 0; r < 4; ++r) {
        cst[r] = sigf(acc[1][r]) * cst[r] + sigmul(acc[0][r], acc[2][r]);
        hb[r]  = (__bf16)sigmul(acc[3][r], cst[r]);
      }
      *(bf16x4*)&sh.h[nxt][kg_w][n16][sub] = hb;
      if (lyr < 2) *(bf16x4*)&sh.hist[s][kg_w][n16][sub] = hb;
      __syncthreads();
    }
  }

  // ---- final flush of hist(NCHUNK-1) + terminal flag ----
  if (lyr < 2) {
    const int m = NCHUNK - 1;
    if (tid == 0) wait_ge(cons_my, m - RSLOT + 1);
    __syncthreads();
    u64* dst = mybuf + (size_t)(m % RSLOT) * CH_U64;
    const u64* hsrc = (const u64*)&sh.hist[0][0][0][0];
    #pragma unroll
    for (int it = 0; it < 8; ++it) {
      const int j = tid + it * NTHREADS;
      adat_store(dst + j, hsrc[j]);
    }
    __syncthreads();   // drains vmcnt(0): data at IC before flag
    if (tid == 0) afl_store(flag_my, NCHUNK);
  }

  // ---- FC head: layer-2 blocks; t=511 (s=7) wrote parity 0 ----
  if (lyr == 2) {
    for (int j = tid; j < BBATCH * H_DIM; j += NTHREADS) {
      const int b = j >> 7, i = j & 127;
      float a = fc1b[i];
      #pragma unroll 8
      for (int k = 0; k < H_DIM; ++k)
        a += (float)sh.h[0][k >> 3][b][k & 7] * fc1w[i * H_DIM + k];
      sh.z[b][i] = fmaxf(a, 0.f);
    }
    __syncthreads();
    if (tid < BBATCH * OUT_DIM) {
      const int b = tid / OUT_DIM, o = tid % OUT_DIM;
      float a = fc2b[o];
      for (int k = 0; k < H_DIM; ++k)
        a += sh.z[b][k] * fc2w[o * H_DIM + k];
      out[(size_t)(bg + b) * OUT_DIM + o] = a;
    }
  }
}

extern "C" void kernel_launch(void* const* d_in, const int* in_sizes, int n_in,
                              void* d_out, int out_size, void* d_ws, size_t ws_size,
                              hipStream_t stream) {
  const float* x    = (const float*)d_in[0];
  const float* wih0 = (const float*)d_in[1];
  const float* whh0 = (const float*)d_in[2];
  const float* bih0 = (const float*)d_in[3];
  const float* bhh0 = (const float*)d_in[4];
  const float* wih1 = (const float*)d_in[5];
  const float* whh1 = (const float*)d_in[6];
  const float* bih1 = (const float*)d_in[7];
  const float* bhh1 = (const float*)d_in[8];
  const float* wih2 = (const float*)d_in[9];
  const float* whh2 = (const float*)d_in[10];
  const float* bih2 = (const float*)d_in[11];
  const float* bhh2 = (const float*)d_in[12];
  const float* fc1w = (const float*)d_in[13];
  const float* fc1b = (const float*)d_in[14];
  const float* fc2w = (const float*)d_in[15];
  const float* fc2b = (const float*)d_in[16];
  float* out  = (float*)d_out;
  __bf16* ws  = (__bf16*)d_ws;   // ~33.7 MB used (weights + flags + ring)

  prep_kernel<<<dim3(175), dim3(256), 0, stream>>>(
      wih0, whh0, bih0, bhh0, wih1, whh1, bih1, bhh1,
      wih2, whh2, bih2, bhh2, ws);
  lstm_kernel<<<dim3(3 * NGRP), dim3(NTHREADS), 0, stream>>>(
      x, fc1w, fc1b, fc2w, fc2b, out, ws);
}